// Round 7
// baseline (333.983 us; speedup 1.0000x reference)
//
#include <hip/hip_runtime.h>
#include <hip/hip_bf16.h>

// Fused: out[m,:] = relu( (softmax_n(relu([pus|pis|pss]@W1+b1)@W2+b2) .
//                          relu([C|pss]@WR+bR)) @ Wo + bo )
// R7: barrier-free per-wave GEMMs. 1 block per m, 256 thr = 4 waves, each wave
// owns 32 rows (2 halves of 16). A-fragments loaded straight from global f32
// (2xfloat4 + cvt) — lane layout (row=lane&15, k=8*(lane>>4)) is contiguous-k.
// B-fragments from chunked weight layout Wp[ck][n][8] (16B/lane, 8 col-frags at
// +256B imm offsets). No LDS staging, no per-step barriers; only 4 syncthreads
// (softmax + pooling). Waves are independent latency-tolerant streams.

#define M_ 4096
#define N_ 100
#define E_ 128

typedef __bf16 bf16x8 __attribute__((ext_vector_type(8)));
typedef float  f32x4  __attribute__((ext_vector_type(4)));

// W1p[ck][n][j] = bf16(W1[ck*8+j][n]), ck<48 (K=384)
// WRp[ck][n][j] = bf16(WR[ck*8+j][n]), ck<32 (K=256)
__global__ void prep_weights(const float* __restrict__ W1, const float* __restrict__ WR,
                             __bf16* __restrict__ W1p, __bf16* __restrict__ WRp) {
    int i = blockIdx.x * 256 + threadIdx.x;          // 320*256 >= 49152+32768
    if (i < 48 * 128 * 8) {
        int ck = i >> 10, n = (i >> 3) & 127, j = i & 7;
        W1p[i] = (__bf16)W1[(ck * 8 + j) * 128 + n];
    } else {
        int t = i - 48 * 128 * 8;
        if (t < 32 * 128 * 8) {
            int ck = t >> 10, n = (t >> 3) & 127, j = t & 7;
            WRp[t] = (__bf16)WR[(ck * 8 + j) * 128 + n];
        }
    }
}

__device__ __forceinline__ bf16x8 cvt8(const float4 lo, const float4 hi) {
    bf16x8 r;
    r[0] = (__bf16)lo.x; r[1] = (__bf16)lo.y; r[2] = (__bf16)lo.z; r[3] = (__bf16)lo.w;
    r[4] = (__bf16)hi.x; r[5] = (__bf16)hi.y; r[6] = (__bf16)hi.z; r[7] = (__bf16)hi.w;
    return r;
}

__global__ __launch_bounds__(256, 3) void fused(
    const float* __restrict__ pus, const float* __restrict__ pis,
    const float* __restrict__ pss, const float* __restrict__ Cc,
    const __bf16* __restrict__ W1p, const float* __restrict__ b1,
    const float* __restrict__ W2, const float* __restrict__ b2,
    const __bf16* __restrict__ WRp, const float* __restrict__ bR,
    const float* __restrict__ Wo, const float* __restrict__ bo,
    float* __restrict__ out)
{
    __shared__ float sLDS[128];
    __shared__ float wLDS[128];
    __shared__ float pairp[4][128];
    __shared__ float pairLDS[128];

    const int tid  = threadIdx.x;
    const int lane = tid & 63;
    const int wid  = tid >> 6;          // 0..3
    const int g    = lane >> 4;         // k-subchunk 0..3
    const int l15  = lane & 15;
    const int m    = blockIdx.x;
    const long base = (long)m * (N_ * E_);
    const int row0 = wid * 32;

    // per-lane A offsets (element units); pad rows clamp to row 99 (masked later)
    int ar0 = row0 + l15;       if (ar0 > N_ - 1) ar0 = N_ - 1;
    int ar1 = row0 + 16 + l15;  if (ar1 > N_ - 1) ar1 = N_ - 1;
    const long aoff0 = base + (long)ar0 * E_ + g * 8;
    const long aoff1 = base + (long)ar1 * E_ + g * 8;
    const int wb = l15 * 8;     // within-chunk B offset (elements)

    f32x4 acc[2][8];
    #pragma unroll
    for (int h = 0; h < 2; ++h)
        #pragma unroll
        for (int cf = 0; cf < 8; ++cf)
            acc[h][cf] = (f32x4){0.f, 0.f, 0.f, 0.f};

    // ---- GEMM1: scores pre-reduce. 12 k-steps of 32, no barriers ----
    #pragma unroll
    for (int kt = 0; kt < 12; ++kt) {
        const float* __restrict__ src = (kt < 4) ? pus : (kt < 8) ? pis : pss;
        const int co = (kt & 3) * 32;
        float4 a0l = *reinterpret_cast<const float4*>(src + aoff0 + co);
        float4 a0h = *reinterpret_cast<const float4*>(src + aoff0 + co + 4);
        float4 a1l = *reinterpret_cast<const float4*>(src + aoff1 + co);
        float4 a1h = *reinterpret_cast<const float4*>(src + aoff1 + co + 4);
        const __bf16* __restrict__ wp = W1p + ((kt * 4 + g) << 10) + wb;
        bf16x8 af0 = cvt8(a0l, a0h);
        bf16x8 af1 = cvt8(a1l, a1h);
        #pragma unroll
        for (int cf = 0; cf < 8; ++cf) {
            bf16x8 bf = *reinterpret_cast<const bf16x8*>(wp + (cf << 7));
            acc[0][cf] = __builtin_amdgcn_mfma_f32_16x16x32_bf16(af0, bf, acc[0][cf], 0, 0, 0);
            acc[1][cf] = __builtin_amdgcn_mfma_f32_16x16x32_bf16(af1, bf, acc[1][cf], 0, 0, 0);
        }
    }

    // ---- scores epilogue: score[row] = sum_col relu(h+b1)*W2 (+b2) ----
    {
        float w2v[8], b1v[8];
        #pragma unroll
        for (int cf = 0; cf < 8; ++cf) {
            w2v[cf] = W2[cf * 16 + l15];
            b1v[cf] = b1[cf * 16 + l15];
        }
        const float b2v = b2[0];
        #pragma unroll
        for (int h = 0; h < 2; ++h) {
            #pragma unroll
            for (int r = 0; r < 4; ++r) {
                float ps = 0.f;
                #pragma unroll
                for (int cf = 0; cf < 8; ++cf)
                    ps += fmaxf(acc[h][cf][r] + b1v[cf], 0.f) * w2v[cf];
                ps += __shfl_xor(ps, 1);
                ps += __shfl_xor(ps, 2);
                ps += __shfl_xor(ps, 4);
                ps += __shfl_xor(ps, 8);
                if (l15 == 0)
                    sLDS[row0 + h * 16 + g * 4 + r] = ps + b2v;
            }
        }
    }
    __syncthreads();

    // ---- softmax over 100 paths (wave 0) ----
    if (wid == 0) {
        float s0 = (lane < N_) ? sLDS[lane] : -3e38f;
        float s1 = (lane + 64 < N_) ? sLDS[lane + 64] : -3e38f;
        float mx = fmaxf(s0, s1);
        #pragma unroll
        for (int off = 1; off < 64; off <<= 1) mx = fmaxf(mx, __shfl_xor(mx, off));
        float e0 = (lane < N_) ? __expf(s0 - mx) : 0.f;
        float e1 = (lane + 64 < N_) ? __expf(s1 - mx) : 0.f;
        float sum = e0 + e1;
        #pragma unroll
        for (int off = 1; off < 64; off <<= 1) sum += __shfl_xor(sum, off);
        float inv = 1.f / sum;
        wLDS[lane]      = e0 * inv;
        wLDS[lane + 64] = e1 * inv;
    }
    __syncthreads();

    // ---- GEMM2: v = relu([C|pss]@WR+bR). 8 k-steps of 32, no barriers ----
    #pragma unroll
    for (int h = 0; h < 2; ++h)
        #pragma unroll
        for (int cf = 0; cf < 8; ++cf)
            acc[h][cf] = (f32x4){0.f, 0.f, 0.f, 0.f};

    #pragma unroll
    for (int kt = 0; kt < 8; ++kt) {
        const float* __restrict__ src = (kt < 4) ? Cc : pss;
        const int co = (kt & 3) * 32;
        float4 a0l = *reinterpret_cast<const float4*>(src + aoff0 + co);
        float4 a0h = *reinterpret_cast<const float4*>(src + aoff0 + co + 4);
        float4 a1l = *reinterpret_cast<const float4*>(src + aoff1 + co);
        float4 a1h = *reinterpret_cast<const float4*>(src + aoff1 + co + 4);
        const __bf16* __restrict__ wp = WRp + ((kt * 4 + g) << 10) + wb;
        bf16x8 af0 = cvt8(a0l, a0h);
        bf16x8 af1 = cvt8(a1l, a1h);
        #pragma unroll
        for (int cf = 0; cf < 8; ++cf) {
            bf16x8 bf = *reinterpret_cast<const bf16x8*>(wp + (cf << 7));
            acc[0][cf] = __builtin_amdgcn_mfma_f32_16x16x32_bf16(af0, bf, acc[0][cf], 0, 0, 0);
            acc[1][cf] = __builtin_amdgcn_mfma_f32_16x16x32_bf16(af1, bf, acc[1][cf], 0, 0, 0);
        }
    }

    // ---- pooling epilogue: pair[col] = sum_rows w[row]*relu(v+bR) ----
    {
        float bRv[8];
        #pragma unroll
        for (int cf = 0; cf < 8; ++cf) bRv[cf] = bR[cf * 16 + l15];
        float wg[2][4];
        #pragma unroll
        for (int h = 0; h < 2; ++h)
            #pragma unroll
            for (int r = 0; r < 4; ++r)
                wg[h][r] = wLDS[row0 + h * 16 + g * 4 + r];
        float psum[8];
        #pragma unroll
        for (int cf = 0; cf < 8; ++cf) psum[cf] = 0.f;
        #pragma unroll
        for (int h = 0; h < 2; ++h)
            #pragma unroll
            for (int cf = 0; cf < 8; ++cf)
                #pragma unroll
                for (int r = 0; r < 4; ++r)
                    psum[cf] += wg[h][r] * fmaxf(acc[h][cf][r] + bRv[cf], 0.f);
        #pragma unroll
        for (int cf = 0; cf < 8; ++cf) {
            psum[cf] += __shfl_xor(psum[cf], 16);
            psum[cf] += __shfl_xor(psum[cf], 32);
        }
        if (lane < 16) {
            #pragma unroll
            for (int cf = 0; cf < 8; ++cf)
                pairp[wid][cf * 16 + lane] = psum[cf];
        }
    }
    __syncthreads();
    if (tid < 128)
        pairLDS[tid] = pairp[0][tid] + pairp[1][tid] + pairp[2][tid] + pairp[3][tid];
    __syncthreads();

    // ---- lout: out[m][e] = relu(sum_k pair[k]*Wo[k][e] + bo[e]) ----
    if (tid < 128) {
        float o = bo[tid];
        #pragma unroll 8
        for (int k = 0; k < 128; ++k)
            o += pairLDS[k] * Wo[k * 128 + tid];
        out[(long)m * 128 + tid] = fmaxf(o, 0.f);
    }
}

extern "C" void kernel_launch(void* const* d_in, const int* in_sizes, int n_in,
                              void* d_out, int out_size, void* d_ws, size_t ws_size,
                              hipStream_t stream) {
    const float* pus = (const float*)d_in[2];
    const float* pis = (const float*)d_in[3];
    const float* pss = (const float*)d_in[4];
    const float* C   = (const float*)d_in[5];
    const float* W1  = (const float*)d_in[6];
    const float* b1  = (const float*)d_in[7];
    const float* W2  = (const float*)d_in[8];
    const float* b2  = (const float*)d_in[9];
    const float* WR  = (const float*)d_in[10];
    const float* bR  = (const float*)d_in[11];
    const float* Wo  = (const float*)d_in[12];
    const float* bo  = (const float*)d_in[13];
    (void)in_sizes; (void)n_in; (void)ws_size;

    // workspace: W1p bf16[48*128*8] | WRp bf16[32*128*8]
    __bf16* W1p = (__bf16*)d_ws;
    __bf16* WRp = W1p + 48 * 128 * 8;

    prep_weights<<<320, 256, 0, stream>>>(W1, WR, W1p, WRp);
    fused<<<M_, 256, 0, stream>>>(pus, pis, pss, C, W1p, b1, W2, b2,
                                  WRp, bR, Wo, bo, (float*)d_out);
}

// Round 8
// 278.004 us; speedup vs baseline: 1.2014x; 1.2014x over previous
//
#include <hip/hip_runtime.h>
#include <hip/hip_bf16.h>

// Fused: out[m,:] = relu( (softmax_n(relu([pus|pis|pss]@W1+b1)@W2+b2) .
//                          relu([C|pss]@WR+bR)) @ Wo + bo )
// R8: A-resident-in-registers. 1 block per m, 256 thr = 4 waves, wave = 32 rows.
// Each lane burst-loads its rows' full K (pus|pis|pss|C = 512 k) as bf16 into
// 128 VGPRs (64 float4 loads in flight at once — deep memory parallelism).
// Both GEMMs then consume A from registers; B comes from chunked L2-resident
// weights (same 16B-coalesced layout as R7, all 4 waves share -> L1 hits).
// pss registers are shared between GEMM1 (k 256..383) and GEMM2 (k 128..255).
// No LDS staging; syncthreads only around softmax / pooling / lout.

#define M_ 4096
#define N_ 100
#define E_ 128

typedef __bf16 bf16x8 __attribute__((ext_vector_type(8)));
typedef float  f32x4  __attribute__((ext_vector_type(4)));

// W1p[ck][n][j] = bf16(W1[ck*8+j][n]), ck<48 (K=384)
// WRp[ck][n][j] = bf16(WR[ck*8+j][n]), ck<32 (K=256)
__global__ void prep_weights(const float* __restrict__ W1, const float* __restrict__ WR,
                             __bf16* __restrict__ W1p, __bf16* __restrict__ WRp) {
    int i = blockIdx.x * 256 + threadIdx.x;          // 320*256 >= 49152+32768
    if (i < 48 * 128 * 8) {
        int ck = i >> 10, n = (i >> 3) & 127, j = i & 7;
        W1p[i] = (__bf16)W1[(ck * 8 + j) * 128 + n];
    } else {
        int t = i - 48 * 128 * 8;
        if (t < 32 * 128 * 8) {
            int ck = t >> 10, n = (t >> 3) & 127, j = t & 7;
            WRp[t] = (__bf16)WR[(ck * 8 + j) * 128 + n];
        }
    }
}

__device__ __forceinline__ bf16x8 cvt8(const float4 lo, const float4 hi) {
    bf16x8 r;
    r[0] = (__bf16)lo.x; r[1] = (__bf16)lo.y; r[2] = (__bf16)lo.z; r[3] = (__bf16)lo.w;
    r[4] = (__bf16)hi.x; r[5] = (__bf16)hi.y; r[6] = (__bf16)hi.z; r[7] = (__bf16)hi.w;
    return r;
}

__global__ __launch_bounds__(256, 2) void fused(
    const float* __restrict__ pus, const float* __restrict__ pis,
    const float* __restrict__ pss, const float* __restrict__ Cc,
    const __bf16* __restrict__ W1p, const float* __restrict__ b1,
    const float* __restrict__ W2, const float* __restrict__ b2,
    const __bf16* __restrict__ WRp, const float* __restrict__ bR,
    const float* __restrict__ Wo, const float* __restrict__ bo,
    float* __restrict__ out)
{
    __shared__ float sLDS[128];
    __shared__ float wLDS[128];
    __shared__ float pairp[4][128];
    __shared__ float pairLDS[128];
    __shared__ float loutp[128];

    const int tid  = threadIdx.x;
    const int lane = tid & 63;
    const int wid  = tid >> 6;          // 0..3
    const int g    = lane >> 4;         // k-subchunk 0..3
    const int l15  = lane & 15;
    const int m    = blockIdx.x;
    const long base = (long)m * (N_ * E_);
    const int row0 = wid * 32;

    // per-lane A row offsets; pad rows clamp to row 99 (masked later by
    // softmax mask / weight=0; clamped re-reads are L1 hits, not extra HBM)
    int ar0 = row0 + l15;       if (ar0 > N_ - 1) ar0 = N_ - 1;
    int ar1 = row0 + 16 + l15;  if (ar1 > N_ - 1) ar1 = N_ - 1;
    long aoff[2];
    aoff[0] = base + (long)ar0 * E_ + g * 8;
    aoff[1] = base + (long)ar1 * E_ + g * 8;
    const int wb = l15 * 8;     // within-chunk B offset (elements)

    // ---- burst-load A: a1[h][kc] covers [pus|pis|pss], a2c[h][kc] covers C ----
    // frag (h,kc): row = row0 + h*16 + l15, k = kc*32 + g*8 + (0..7)
    bf16x8 a1[2][12];
    bf16x8 a2c[2][4];
    #pragma unroll
    for (int h = 0; h < 2; ++h) {
        #pragma unroll
        for (int kc = 0; kc < 12; ++kc) {
            const float* __restrict__ src = (kc < 4) ? pus : (kc < 8) ? pis : pss;
            const int co = (kc & 3) * 32;
            float4 lo = *reinterpret_cast<const float4*>(src + aoff[h] + co);
            float4 hi = *reinterpret_cast<const float4*>(src + aoff[h] + co + 4);
            a1[h][kc] = cvt8(lo, hi);
        }
        #pragma unroll
        for (int kc = 0; kc < 4; ++kc) {
            const int co = kc * 32;
            float4 lo = *reinterpret_cast<const float4*>(Cc + aoff[h] + co);
            float4 hi = *reinterpret_cast<const float4*>(Cc + aoff[h] + co + 4);
            a2c[h][kc] = cvt8(lo, hi);
        }
    }

    f32x4 acc[2][8];
    #pragma unroll
    for (int h = 0; h < 2; ++h)
        #pragma unroll
        for (int cf = 0; cf < 8; ++cf)
            acc[h][cf] = (f32x4){0.f, 0.f, 0.f, 0.f};

    // ---- GEMM1: A from regs, B from L2 (shared across waves -> L1) ----
    #pragma unroll
    for (int kc = 0; kc < 12; ++kc) {
        const __bf16* __restrict__ wp = W1p + ((kc * 4 + g) << 10) + wb;
        #pragma unroll
        for (int cf = 0; cf < 8; ++cf) {
            bf16x8 bf = *reinterpret_cast<const bf16x8*>(wp + (cf << 7));
            acc[0][cf] = __builtin_amdgcn_mfma_f32_16x16x32_bf16(a1[0][kc], bf, acc[0][cf], 0, 0, 0);
            acc[1][cf] = __builtin_amdgcn_mfma_f32_16x16x32_bf16(a1[1][kc], bf, acc[1][cf], 0, 0, 0);
        }
    }

    // ---- scores epilogue: score[row] = sum_col relu(h+b1)*W2 (+b2) ----
    {
        float w2v[8], b1v[8];
        #pragma unroll
        for (int cf = 0; cf < 8; ++cf) {
            w2v[cf] = W2[cf * 16 + l15];
            b1v[cf] = b1[cf * 16 + l15];
        }
        const float b2v = b2[0];
        #pragma unroll
        for (int h = 0; h < 2; ++h) {
            #pragma unroll
            for (int r = 0; r < 4; ++r) {
                float ps = 0.f;
                #pragma unroll
                for (int cf = 0; cf < 8; ++cf)
                    ps += fmaxf(acc[h][cf][r] + b1v[cf], 0.f) * w2v[cf];
                ps += __shfl_xor(ps, 1);
                ps += __shfl_xor(ps, 2);
                ps += __shfl_xor(ps, 4);
                ps += __shfl_xor(ps, 8);
                if (l15 == 0)
                    sLDS[row0 + h * 16 + g * 4 + r] = ps + b2v;
            }
        }
    }
    __syncthreads();

    // ---- softmax over 100 paths (wave 0) ----
    if (wid == 0) {
        float s0 = (lane < N_) ? sLDS[lane] : -3e38f;
        float s1 = (lane + 64 < N_) ? sLDS[lane + 64] : -3e38f;
        float mx = fmaxf(s0, s1);
        #pragma unroll
        for (int off = 1; off < 64; off <<= 1) mx = fmaxf(mx, __shfl_xor(mx, off));
        float e0 = (lane < N_) ? __expf(s0 - mx) : 0.f;
        float e1 = (lane + 64 < N_) ? __expf(s1 - mx) : 0.f;
        float sum = e0 + e1;
        #pragma unroll
        for (int off = 1; off < 64; off <<= 1) sum += __shfl_xor(sum, off);
        float inv = 1.f / sum;
        wLDS[lane]      = e0 * inv;
        wLDS[lane + 64] = e1 * inv;
    }
    __syncthreads();

    // ---- GEMM2: A from regs (C frags + shared pss frags), B from WRp ----
    #pragma unroll
    for (int h = 0; h < 2; ++h)
        #pragma unroll
        for (int cf = 0; cf < 8; ++cf)
            acc[h][cf] = (f32x4){0.f, 0.f, 0.f, 0.f};

    #pragma unroll
    for (int kc = 0; kc < 8; ++kc) {
        const __bf16* __restrict__ wp = WRp + ((kc * 4 + g) << 10) + wb;
        #pragma unroll
        for (int cf = 0; cf < 8; ++cf) {
            bf16x8 bf = *reinterpret_cast<const bf16x8*>(wp + (cf << 7));
            #pragma unroll
            for (int h = 0; h < 2; ++h) {
                bf16x8 af = (kc < 4) ? a2c[h][kc] : a1[h][8 + (kc - 4)];
                acc[h][cf] = __builtin_amdgcn_mfma_f32_16x16x32_bf16(af, bf, acc[h][cf], 0, 0, 0);
            }
        }
    }

    // ---- pooling epilogue: pair[col] = sum_rows w[row]*relu(v+bR) ----
    {
        float bRv[8];
        #pragma unroll
        for (int cf = 0; cf < 8; ++cf) bRv[cf] = bR[cf * 16 + l15];
        float wg[2][4];
        #pragma unroll
        for (int h = 0; h < 2; ++h)
            #pragma unroll
            for (int r = 0; r < 4; ++r)
                wg[h][r] = wLDS[row0 + h * 16 + g * 4 + r];
        float psum[8];
        #pragma unroll
        for (int cf = 0; cf < 8; ++cf) psum[cf] = 0.f;
        #pragma unroll
        for (int h = 0; h < 2; ++h)
            #pragma unroll
            for (int cf = 0; cf < 8; ++cf)
                #pragma unroll
                for (int r = 0; r < 4; ++r)
                    psum[cf] += wg[h][r] * fmaxf(acc[h][cf][r] + bRv[cf], 0.f);
        #pragma unroll
        for (int cf = 0; cf < 8; ++cf) {
            psum[cf] += __shfl_xor(psum[cf], 16);
            psum[cf] += __shfl_xor(psum[cf], 32);
        }
        if (lane < 16) {
            #pragma unroll
            for (int cf = 0; cf < 8; ++cf)
                pairp[wid][cf * 16 + lane] = psum[cf];
        }
    }
    __syncthreads();
    if (tid < 128)
        pairLDS[tid] = pairp[0][tid] + pairp[1][tid] + pairp[2][tid] + pairp[3][tid];
    __syncthreads();

    // ---- lout, split-K over 2 thread-halves ----
    {
        const int e  = tid & 127;
        const int hf = tid >> 7;
        float o = 0.f;
        #pragma unroll 8
        for (int k = 0; k < 64; ++k) {
            int kk = hf * 64 + k;
            o += pairLDS[kk] * Wo[kk * 128 + e];
        }
        if (hf == 1) loutp[e] = o;
        __syncthreads();
        if (hf == 0)
            out[(long)m * 128 + e] = fmaxf(o + loutp[e] + bo[e], 0.f);
    }
}

extern "C" void kernel_launch(void* const* d_in, const int* in_sizes, int n_in,
                              void* d_out, int out_size, void* d_ws, size_t ws_size,
                              hipStream_t stream) {
    const float* pus = (const float*)d_in[2];
    const float* pis = (const float*)d_in[3];
    const float* pss = (const float*)d_in[4];
    const float* C   = (const float*)d_in[5];
    const float* W1  = (const float*)d_in[6];
    const float* b1  = (const float*)d_in[7];
    const float* W2  = (const float*)d_in[8];
    const float* b2  = (const float*)d_in[9];
    const float* WR  = (const float*)d_in[10];
    const float* bR  = (const float*)d_in[11];
    const float* Wo  = (const float*)d_in[12];
    const float* bo  = (const float*)d_in[13];
    (void)in_sizes; (void)n_in; (void)ws_size;

    // workspace: W1p bf16[48*128*8] | WRp bf16[32*128*8]
    __bf16* W1p = (__bf16*)d_ws;
    __bf16* WRp = W1p + 48 * 128 * 8;

    prep_weights<<<320, 256, 0, stream>>>(W1, WR, W1p, WRp);
    fused<<<M_, 256, 0, stream>>>(pus, pis, pss, C, W1p, b1, W2, b2,
                                  WRp, bR, Wo, bo, (float*)d_out);
}